// Round 10
// baseline (227.510 us; speedup 1.0000x reference)
//
#include <hip/hip_runtime.h>
#include <hip/hip_bf16.h>

typedef float f32x4 __attribute__((ext_vector_type(4)));
typedef short s16x8 __attribute__((ext_vector_type(8)));
typedef unsigned short u16;

#define B_ 2
#define S_ 2048
#define HID 1536
#define NQ_ 24
#define NKV_ 4
#define HD 64
#define NTOK (B_*S_)
#define QKVN ((NQ_+2*NKV_)*HD)   // 2048
#define ROPE_BLOCKS ((NTOK*28*32)/256)   // 14336
#define VT_BLOCKS (B_*NKV_*(S_/64))      // 256

// Compiler-only memory fence (single-wave block: LDS pipe is in-order, no s_barrier
// needed -> avoids the vmcnt(0) drain). Proven R6->R7 on k_attn.
#define LDS_FENCE() asm volatile("" ::: "memory")

// Counted-vmcnt barrier pair (T4): wait for all but the newest N loads, then raw
// s_barrier -- deliberately does NOT drain the in-flight prefetch (unlike
// __syncthreads, which the compiler lowers with a full vmcnt(0) drain).
#define WAITBAR(n) asm volatile("s_waitcnt vmcnt(" #n ")\n\ts_barrier" ::: "memory")
#define RAWBAR()   asm volatile("s_barrier" ::: "memory")

__device__ __forceinline__ float bf2f(u16 u) {
  unsigned int x = ((unsigned int)u) << 16;
  float f; __builtin_memcpy(&f, &x, 4); return f;
}
__device__ __forceinline__ u16 f2bf(float f) {
  unsigned int u; __builtin_memcpy(&u, &f, 4);
  u += 0x7fffu + ((u >> 16) & 1u);
  return (u16)(u >> 16);
}
// 4x f32 -> packed bf16x4 via v_cvt_pk_bf16_f32
__device__ __forceinline__ unsigned long long pk4bf(float a, float b, float c, float d) {
  __hip_bfloat162 x = __float22bfloat162_rn(make_float2(a, b));
  __hip_bfloat162 y = __float22bfloat162_rn(make_float2(c, d));
  unsigned int xi, yi;
  __builtin_memcpy(&xi, &x, 4);
  __builtin_memcpy(&yi, &y, 4);
  return (unsigned long long)xi | ((unsigned long long)yi << 32);
}

// ---------------- fused fp32 -> bf16 conversion of both weight matrices ----------------
__global__ __launch_bounds__(256) void k_cvt2(const float* __restrict__ s0, int n0q,
                                              const float* __restrict__ s1, int n1q,
                                              u16* __restrict__ dst) {
  int i = blockIdx.x * 256 + threadIdx.x;   // units of 4 elements
  if (i >= n0q + n1q) return;
  const float* src = (i < n0q) ? s0 : s1;
  int j = (i < n0q) ? i : i - n0q;
  f32x4 v = ((const f32x4*)src)[j];
  *(unsigned long long*)(dst + (size_t)i*4) = pk4bf(v[0], v[1], v[2], v[3]);
}

// ---------------- RMSNorm (fused fp32 read -> bf16 write) ----------------
__global__ __launch_bounds__(384) void k_rmsnorm(const float* __restrict__ x,
                                                 const float* __restrict__ g,
                                                 u16* __restrict__ xn) {
  int row = blockIdx.x;
  int t = threadIdx.x;
  f32x4 v = ((const f32x4*)(x + (size_t)row * HID))[t];
  float ss = v[0]*v[0] + v[1]*v[1] + v[2]*v[2] + v[3]*v[3];
#pragma unroll
  for (int off = 1; off < 64; off <<= 1) ss += __shfl_xor(ss, off);
  __shared__ float red[6];
  if ((t & 63) == 0) red[t >> 6] = ss;
  __syncthreads();
  float tot = red[0] + red[1] + red[2] + red[3] + red[4] + red[5];
  float rs = rsqrtf(tot * (1.f/HID) + 1e-6f);
  f32x4 gv = ((const f32x4*)g)[t];
  ((unsigned long long*)(xn + (size_t)row * HID))[t] =
      pk4bf(v[0]*rs*gv[0], v[1]*rs*gv[1], v[2]*rs*gv[2], v[3]*rs*gv[3]);
}

// ---------------- GEMM C[M][N] = A[M][K] @ W[N][K]^T, M fixed = 4096 ----------------
// R14: counted-vmcnt depth-2 pipeline. R9 counters (MfmaUtil 15%, 1.35TB/s, 46us)
// showed the old __syncthreads drained vmcnt(0) -- waiting for the JUST-issued t+1
// stage with only ~300cy of cover vs ~1500cy contended latency. New schedule:
// prologue stages t0+t1; per tile: COMPUTE(t); RAWBAR (read-WAR); STAGE(t+2) into
// the freed buffer; WAITBAR(8) = "t+1 landed, t+2 stays in flight". Each tile's
// loads now get >= 1 full iteration of cover and are never force-drained.
// T2 XOR slot-swizzle + XCD M-stripe swizzle kept from R10.
template <bool F32OUT>
__global__ __launch_bounds__(256) void k_gemm_bt(const u16* __restrict__ A,
                                                 const u16* __restrict__ W,
                                                 void* __restrict__ Cv,
                                                 const float* __restrict__ resid,
                                                 int N, int K) {
  __shared__ __align__(16) u16 As0[128*64], Bs0[128*64];
  __shared__ __align__(16) u16 As1[128*64], Bs1[128*64];
  int lin = blockIdx.x;
  int xcd = lin & 7, loc = lin >> 3;
  int mloc = loc & 3, nloc = loc >> 2;          // stripe height 4 (32 Mtiles / 8 XCDs)
  int m0 = (xcd*4 + mloc) * 128, n0 = nloc * 128;
  int tid = threadIdx.x;
  int w = tid >> 6, l = tid & 63;
  int wr = w >> 1, wc = w & 1;
  int c = l & 15, g = l >> 4;
  f32x4 acc[4][4] = {};
  int r8 = l >> 3;                  // row within the 8-row group = (row & 7)
  int sslot = (l & 7) ^ r8;         // swizzled 16B-slot index in the source row
  const u16* Ag = A + (size_t)(m0 + w*32 + r8)*K + sslot*8;
  const u16* Wg = W + (size_t)(n0 + w*32 + r8)*K + sslot*8;

#define STAGE(dA, dB, k0) do {                                                          \
  _Pragma("unroll")                                                                     \
  for (int i = 0; i < 4; i++) {                                                         \
    __builtin_amdgcn_global_load_lds(                                                   \
        (const __attribute__((address_space(1))) void*)(Ag + (size_t)(i*8)*K + (k0)),   \
        (__attribute__((address_space(3))) void*)(dA + (w*32 + i*8)*64), 16, 0, 0);     \
    __builtin_amdgcn_global_load_lds(                                                   \
        (const __attribute__((address_space(1))) void*)(Wg + (size_t)(i*8)*K + (k0)),   \
        (__attribute__((address_space(3))) void*)(dB + (w*32 + i*8)*64), 16, 0, 0);     \
  } } while (0)

#define COMPUTE(sA, sB) do {                                                            \
  _Pragma("unroll")                                                                     \
  for (int ks = 0; ks < 2; ks++) {                                                      \
    s16x8 af[4], bq[4];                                                                 \
    int sl = ((ks*4 + g) ^ (c & 7)) * 8;                                                \
    _Pragma("unroll")                                                                   \
    for (int mt = 0; mt < 4; mt++)                                                      \
      af[mt] = *(const s16x8*)(sA + (wr*64 + mt*16 + c)*64 + sl);                       \
    _Pragma("unroll")                                                                   \
    for (int nt = 0; nt < 4; nt++)                                                      \
      bq[nt] = *(const s16x8*)(sB + (wc*64 + nt*16 + c)*64 + sl);                       \
    _Pragma("unroll")                                                                   \
    for (int mt = 0; mt < 4; mt++)                                                      \
      _Pragma("unroll")                                                                 \
      for (int nt = 0; nt < 4; nt++)                                                    \
        acc[mt][nt] = __builtin_amdgcn_mfma_f32_16x16x32_bf16(af[mt], bq[nt],           \
                                                              acc[mt][nt], 0, 0, 0);    \
  } } while (0)

  const int NT = K >> 6;            // 24 K-tiles of 64 (even, >= 4)
  STAGE(As0, Bs0, 0);
  STAGE(As1, Bs1, 64);
  WAITBAR(8);                       // tile0 landed; tile1 in flight
  for (int t = 0; t + 2 < NT; t += 2) {
    COMPUTE(As0, Bs0);              // tile t (landed)
    RAWBAR();                       // all waves done reading As0/Bs0
    STAGE(As0, Bs0, (t+2)*64);
    WAITBAR(8);                     // tile t+1 landed; t+2 in flight
    COMPUTE(As1, Bs1);              // tile t+1
    RAWBAR();                       // all waves done reading As1/Bs1
    if (t + 3 < NT) {
      STAGE(As1, Bs1, (t+3)*64);
      WAITBAR(8);                   // tile t+2 landed; t+3 in flight
    } else {
      WAITBAR(0);
    }
  }
  COMPUTE(As0, Bs0);                // tile NT-2 (landed via last WAITBAR)
  WAITBAR(0);                       // tile NT-1 landed
  COMPUTE(As1, Bs1);                // tile NT-1
#undef STAGE
#undef COMPUTE

#pragma unroll
  for (int mt = 0; mt < 4; mt++)
#pragma unroll
    for (int nt = 0; nt < 4; nt++)
#pragma unroll
      for (int r = 0; r < 4; r++) {
        int m = m0 + wr*64 + mt*16 + g*4 + r;
        int n = n0 + wc*64 + nt*16 + c;
        size_t off = (size_t)m*N + n;
        float vv = acc[mt][nt][r];
        if (F32OUT) {
          ((float*)Cv)[off] = vv + resid[off];
        } else {
          ((u16*)Cv)[off] = f2bf(vv);
        }
      }
}

// ---------------- fused RoPE(q,k) + V transpose (one launch) ----------------
__global__ __launch_bounds__(256) void k_rope_vt(const u16* __restrict__ qkv,
                                                 u16* __restrict__ q,
                                                 u16* __restrict__ k,
                                                 u16* __restrict__ vt,
                                                 const int* __restrict__ spp) {
  __shared__ u16 tile[64][65];
  int bid = blockIdx.x;
  if (bid < ROPE_BLOCKS) {
    int idx = bid * 256 + threadIdx.x;     // (tok*28 + h)*32 + p
    int p = idx & 31;
    int h = (idx >> 5) % 28;
    int tok = idx / 896;
    int s = tok & (S_ - 1);
    int b = tok >> 11;
    float t = (float)(spp[0] + s);
    // 10000^(-p/32) = exp2(-p * log2(10000)/32); avoids the runtime log in powf
    float inv = exp2f((float)p * -0.41524101186f);
    float fr = t * inv;
    float sn, cs;
    sincosf(fr, &sn, &cs);
    int col = (h < NQ_) ? h*64 + 2*p : HID + (h - NQ_)*64 + 2*p;
    unsigned int pr = *(const unsigned int*)(qkv + (size_t)tok*QKVN + col);
    float x1 = bf2f((u16)(pr & 0xffff));
    float x2 = bf2f((u16)(pr >> 16));
    float y1 = x1*cs - x2*sn;
    float y2 = x2*cs + x1*sn;
    unsigned int outp = (unsigned int)f2bf(y1) | ((unsigned int)f2bf(y2) << 16);
    if (h < NQ_) {
      *(unsigned int*)(q + (((size_t)(b*NQ_ + h))*S_ + s)*64 + 2*p) = outp;
    } else {
      *(unsigned int*)(k + (((size_t)(b*NKV_ + (h - NQ_)))*S_ + s)*64 + 2*p) = outp;
    }
  } else {
    int blk = bid - ROPE_BLOCKS;
    int st = blk & 31;
    int hk = (blk >> 5) & 3;
    int b = blk >> 7;
    int s0 = st * 64;
#pragma unroll
    for (int i = 0; i < 16; i++) {
      int ii = threadIdx.x + i*256;
      int r = ii >> 6, cc = ii & 63;
      tile[r][cc] = qkv[((size_t)(b*S_) + s0 + r)*QKVN + (NQ_+NKV_)*64 + hk*64 + cc];
    }
    __syncthreads();
#pragma unroll
    for (int i = 0; i < 16; i++) {
      int ii = threadIdx.x + i*256;
      int d = ii >> 6, s = ii & 63;
      vt[((size_t)(b*NKV_ + hk)*64 + d)*S_ + s0 + s] = tile[s][d];
    }
  }
}

// ---------------- Flash attention, one wave per (b,h,16-query tile) ----------------
// R14: the R11 16-row occupancy play, this time with the MEASURED VGPR rule honored
// (budget ~= 256*2/min_waves: w=3 -> 85, w=4 -> 64, w=5 -> 48; R7/R8 spilled because
// 5/4-wave bounds capped below the ~80 live regs). (64,3) caps at 85 -- the 32-row
// version fit 84, and this one has 24 fewer live regs (half qf/o) -> no spill, and
// at ~80 VGPR the HW allows 6 waves/SIMD. Grid 6144 = 24 blocks/CU supplies them:
// 2x R4's wave count, 4 qb strata per CU (balance), same total MFMA+softmax work
// (window 256 -> a 16-row tile covers the same ~5 K-tiles as 32-row).
__global__ __launch_bounds__(64, 3) void k_attn(const u16* __restrict__ q,
                                                const u16* __restrict__ k,
                                                const u16* __restrict__ vt,
                                                u16* __restrict__ ao,
                                                const int* __restrict__ spp) {
  __shared__ __align__(16) u16 Pt[16*72];
  int lin = blockIdx.x;
  // XCD-aware swizzle (bid&7 = XCD): each XCD gets all 128 q-tiles of 6 consecutive
  // heads sharing one (b,hk) K/V pair (512KB, L2-resident).
  int xcd = lin & 7, loc = lin >> 3;   // loc in [0,768)
  int qb = loc & 127;
  int bh = xcd * 6 + (loc >> 7);       // [0,48)
  int h = bh % NQ_;
  int b = bh / NQ_;
  int q0 = qb * 16;
  int hk = h / (NQ_/NKV_);
  int l = threadIdx.x;
  int c = l & 15, g = l >> 4;
  int sp = spp[0];
  const u16* qptr = q + ((size_t)(b*NQ_ + h))*S_*64;
  const u16* kptr = k + ((size_t)(b*NKV_ + hk))*S_*64;
  const u16* vptr = vt + ((size_t)(b*NKV_ + hk))*64*S_;

  s16x8 qf[2];
#pragma unroll
  for (int ks = 0; ks < 2; ks++)
    qf[ks] = *(const s16x8*)(qptr + (size_t)(q0 + c)*64 + ks*32 + g*8);

  f32x4 o[4] = {};             // o[dt]: O^T accum, row=d col=q
  float m_run = -1e30f, l_run = 0.f;

  int lo = sp + q0 - 256; if (lo < 0) lo = 0;
  int hi = sp + q0 + 15;  if (hi > S_ - 1) hi = S_ - 1;
  int kt0 = lo >> 6, kt1 = hi >> 6;

  s16x8 kf[4][2];
#pragma unroll
  for (int km = 0; km < 4; km++)
#pragma unroll
    for (int ks = 0; ks < 2; ks++)
      kf[km][ks] = *(const s16x8*)(kptr + (size_t)(kt0*64 + km*16 + c)*64 + ks*32 + g*8);

  for (int kt = kt0; kt <= kt1; kt++) {
    // V(kt) issued first: consumed at PV, covered by QK + kf prefetch + softmax.
    s16x8 vf[2][4];
#pragma unroll
    for (int ks = 0; ks < 2; ks++)
#pragma unroll
      for (int dt = 0; dt < 4; dt++)
        vf[ks][dt] = *(const s16x8*)(vptr + (size_t)(dt*16 + c)*S_ + kt*64 + ks*32 + g*8);

    // full tile: no masking needed for any (query,key) pair
    bool full = (kt*64 + 63 <= sp + q0) && (kt*64 >= sp + q0 - 241);
    f32x4 sa[4];               // S^T tile: row=key col=query
    __builtin_amdgcn_s_setprio(1);
#pragma unroll
    for (int km = 0; km < 4; km++) {
      f32x4 z = {};
      z = __builtin_amdgcn_mfma_f32_16x16x32_bf16(kf[km][0], qf[0], z, 0, 0, 0);
      sa[km] = __builtin_amdgcn_mfma_f32_16x16x32_bf16(kf[km][1], qf[1], z, 0, 0, 0);
    }
    __builtin_amdgcn_s_setprio(0);
    if (kt < kt1) {
      // K(kt+1) prefetch right after kf's last use; covered by softmax + PV.
#pragma unroll
      for (int km = 0; km < 4; km++)
#pragma unroll
        for (int ks = 0; ks < 2; ks++)
          kf[km][ks] = *(const s16x8*)(kptr + (size_t)((kt+1)*64 + km*16 + c)*64 + ks*32 + g*8);
    }
    float mx = -1e30f;
    if (full) {
#pragma unroll
      for (int km = 0; km < 4; km++)
#pragma unroll
        for (int r = 0; r < 4; r++) {
          float sv = sa[km][r] * 0.125f;
          sa[km][r] = sv;
          mx = fmaxf(mx, sv);
        }
    } else {
      int pos = sp + q0 + c;
#pragma unroll
      for (int km = 0; km < 4; km++)
#pragma unroll
        for (int r = 0; r < 4; r++) {
          int key = kt*64 + km*16 + g*4 + r;
          float sv = sa[km][r] * 0.125f;
          sv = ((unsigned)(pos - key) <= 256u) ? sv : -1e30f;
          sa[km][r] = sv;
          mx = fmaxf(mx, sv);
        }
    }
    mx = fmaxf(mx, __shfl_xor(mx, 16));
    mx = fmaxf(mx, __shfl_xor(mx, 32));
    float mnew = fmaxf(m_run, mx);
    float alpha = __expf(m_run - mnew);
    m_run = mnew;
    float rsum = 0.f;
#pragma unroll
    for (int km = 0; km < 4; km++) {
      float p0 = __expf(sa[km][0] - mnew);   // masked -1e30 underflows to 0
      float p1 = __expf(sa[km][1] - mnew);
      float p2 = __expf(sa[km][2] - mnew);
      float p3 = __expf(sa[km][3] - mnew);
      rsum += p0 + p1 + p2 + p3;
      *(unsigned long long*)(Pt + c*72 + km*16 + g*4) = pk4bf(p0, p1, p2, p3);
    }
    rsum += __shfl_xor(rsum, 16);
    rsum += __shfl_xor(rsum, 32);
    l_run = l_run*alpha + rsum;
#pragma unroll
    for (int dt = 0; dt < 4; dt++) {
      o[dt][0] *= alpha; o[dt][1] *= alpha;
      o[dt][2] *= alpha; o[dt][3] *= alpha;
    }
    LDS_FENCE();   // Pt writes ordered before reads (in-order DS pipe, same wave)
    // PV: O^T += V^T @ P^T
    __builtin_amdgcn_s_setprio(1);
#pragma unroll
    for (int ks = 0; ks < 2; ks++) {
      s16x8 pf = *(const s16x8*)(Pt + c*72 + ks*32 + g*8);
#pragma unroll
      for (int dt = 0; dt < 4; dt++)
        o[dt] = __builtin_amdgcn_mfma_f32_16x16x32_bf16(vf[ks][dt], pf, o[dt], 0, 0, 0);
    }
    __builtin_amdgcn_s_setprio(0);
    LDS_FENCE();   // Pt reads ordered before next iteration's writes
  }
  float inv = 1.f / l_run;
  int qi = q0 + c;
  u16* row = ao + ((size_t)(b*S_) + qi)*HID + h*64;
#pragma unroll
  for (int dt = 0; dt < 4; dt++)
    *(unsigned long long*)(row + dt*16 + g*4) =
        pk4bf(o[dt][0]*inv, o[dt][1]*inv, o[dt][2]*inv, o[dt][3]*inv);
}

extern "C" void kernel_launch(void* const* d_in, const int* in_sizes, int n_in,
                              void* d_out, int out_size, void* d_ws, size_t ws_size,
                              hipStream_t stream) {
  const float* x_f32    = (const float*)d_in[0];
  const float* g_f32    = (const float*)d_in[1];
  const float* wqkv_f32 = (const float*)d_in[2];
  const float* wout_f32 = (const float*)d_in[3];
  const int*   spp      = (const int*)d_in[4];
  char* ws = (char*)d_ws;
  // workspace layout (bytes), ~57.1 MB total
  u16* wqkvb = (u16*)(ws);                    //  6,291,456
  u16* woutb = (u16*)(ws + 6291456);          //  4,718,592 (contiguous with wqkvb)
  u16* xn    = (u16*)(ws + 11010048);         // 12,582,912
  u16* qkv   = (u16*)(ws + 23592960);         // 16,777,216
  u16* qbuf  = (u16*)(ws + 40370176);         // 12,582,912
  u16* kbuf  = (u16*)(ws + 52953088);         //  2,097,152
  u16* vtb   = (u16*)(ws + 55050240);         //  2,097,152  (end 57,147,392)
  u16* attn  = xn;                            // aliases xn (dead after GEMM1)

  const int nwq4 = QKVN*HID/4, nwo4 = HID*HID/4;
  k_cvt2<<<(nwq4 + nwo4 + 255)/256, 256, 0, stream>>>(wqkv_f32, nwq4, wout_f32, nwo4, wqkvb);
  k_rmsnorm<<<NTOK, 384, 0, stream>>>(x_f32, g_f32, xn);
  k_gemm_bt<false><<<32*(QKVN/128), 256, 0, stream>>>(xn, wqkvb, qkv, nullptr, QKVN, HID);
  k_rope_vt<<<ROPE_BLOCKS + VT_BLOCKS, 256, 0, stream>>>(qkv, qbuf, kbuf, vtb, spp);
  k_attn<<<B_*NQ_*(S_/16), 64, 0, stream>>>(qbuf, kbuf, vtb, attn, spp);
  k_gemm_bt<true><<<32*(HID/128), 256, 0, stream>>>(attn, woutb, d_out, x_f32, HID, HID);
}

// Round 11
// 208.679 us; speedup vs baseline: 1.0902x; 1.0902x over previous
//
#include <hip/hip_runtime.h>
#include <hip/hip_bf16.h>

typedef float f32x4 __attribute__((ext_vector_type(4)));
typedef short s16x8 __attribute__((ext_vector_type(8)));
typedef unsigned short u16;

#define B_ 2
#define S_ 2048
#define HID 1536
#define NQ_ 24
#define NKV_ 4
#define HD 64
#define NTOK (B_*S_)
#define QKVN ((NQ_+2*NKV_)*HD)   // 2048
#define ROPE_BLOCKS ((NTOK*28*32)/256)   // 14336
#define VT_BLOCKS (B_*NKV_*(S_/64))      // 256

// Compiler-only memory fence (single-wave block: LDS pipe is in-order, no s_barrier
// needed -> avoids the vmcnt(0) drain). Proven R6->R7 on k_attn.
#define LDS_FENCE() asm volatile("" ::: "memory")

// Counted-vmcnt barrier pair (T4): wait for all but the newest N loads, then raw
// s_barrier -- deliberately does NOT drain the in-flight prefetch (unlike
// __syncthreads, which the compiler lowers with a full vmcnt(0) drain).
#define WAITBAR(n) asm volatile("s_waitcnt vmcnt(" #n ")\n\ts_barrier" ::: "memory")
#define RAWBAR()   asm volatile("s_barrier" ::: "memory")

__device__ __forceinline__ float bf2f(u16 u) {
  unsigned int x = ((unsigned int)u) << 16;
  float f; __builtin_memcpy(&f, &x, 4); return f;
}
__device__ __forceinline__ u16 f2bf(float f) {
  unsigned int u; __builtin_memcpy(&u, &f, 4);
  u += 0x7fffu + ((u >> 16) & 1u);
  return (u16)(u >> 16);
}
// 4x f32 -> packed bf16x4 via v_cvt_pk_bf16_f32
__device__ __forceinline__ unsigned long long pk4bf(float a, float b, float c, float d) {
  __hip_bfloat162 x = __float22bfloat162_rn(make_float2(a, b));
  __hip_bfloat162 y = __float22bfloat162_rn(make_float2(c, d));
  unsigned int xi, yi;
  __builtin_memcpy(&xi, &x, 4);
  __builtin_memcpy(&yi, &y, 4);
  return (unsigned long long)xi | ((unsigned long long)yi << 32);
}

// ---------------- fused fp32 -> bf16 conversion of both weight matrices ----------------
__global__ __launch_bounds__(256) void k_cvt2(const float* __restrict__ s0, int n0q,
                                              const float* __restrict__ s1, int n1q,
                                              u16* __restrict__ dst) {
  int i = blockIdx.x * 256 + threadIdx.x;   // units of 4 elements
  if (i >= n0q + n1q) return;
  const float* src = (i < n0q) ? s0 : s1;
  int j = (i < n0q) ? i : i - n0q;
  f32x4 v = ((const f32x4*)src)[j];
  *(unsigned long long*)(dst + (size_t)i*4) = pk4bf(v[0], v[1], v[2], v[3]);
}

// ---------------- RMSNorm (fused fp32 read -> bf16 write) ----------------
__global__ __launch_bounds__(384) void k_rmsnorm(const float* __restrict__ x,
                                                 const float* __restrict__ g,
                                                 u16* __restrict__ xn) {
  int row = blockIdx.x;
  int t = threadIdx.x;
  f32x4 v = ((const f32x4*)(x + (size_t)row * HID))[t];
  float ss = v[0]*v[0] + v[1]*v[1] + v[2]*v[2] + v[3]*v[3];
#pragma unroll
  for (int off = 1; off < 64; off <<= 1) ss += __shfl_xor(ss, off);
  __shared__ float red[6];
  if ((t & 63) == 0) red[t >> 6] = ss;
  __syncthreads();
  float tot = red[0] + red[1] + red[2] + red[3] + red[4] + red[5];
  float rs = rsqrtf(tot * (1.f/HID) + 1e-6f);
  f32x4 gv = ((const f32x4*)g)[t];
  ((unsigned long long*)(xn + (size_t)row * HID))[t] =
      pk4bf(v[0]*rs*gv[0], v[1]*rs*gv[1], v[2]*rs*gv[2], v[3]*rs*gv[3]);
}

// ---------------- GEMM C[M][N] = A[M][K] @ W[N][K]^T, M fixed = 4096 ----------------
// R15: block-parallelism fix. R10 showed the counted-vmcnt schedule alone was
// neutral -- with 2 blocks/CU, one COMPUTE (~300cy) of cover can't hide ~1500cy
// load latency. BN 128 -> 64 doubles the grid: GEMM1 1024 blocks (4/CU), GEMM2 768
// (3/CU); LDS 48KB -> 3 resident blocks/CU = 12 waves/CU. While one block waits at
// its WAITBAR, the other two blocks' waves feed the MFMA pipe (m114 overlap).
// Counted vmcnt (6 loads/stage), T2 XOR slot-swizzle, XCD M-stripe all kept.
template <bool F32OUT>
__global__ __launch_bounds__(256) void k_gemm_bt(const u16* __restrict__ A,
                                                 const u16* __restrict__ W,
                                                 void* __restrict__ Cv,
                                                 const float* __restrict__ resid,
                                                 int N, int K) {
  __shared__ __align__(16) u16 As0[128*64], Bs0[64*64];
  __shared__ __align__(16) u16 As1[128*64], Bs1[64*64];
  int lin = blockIdx.x;
  int xcd = lin & 7, loc = lin >> 3;
  int mloc = loc & 3, nloc = loc >> 2;          // stripe height 4 (32 Mtiles / 8 XCDs)
  int m0 = (xcd*4 + mloc) * 128, n0 = nloc * 64;
  int tid = threadIdx.x;
  int w = tid >> 6, l = tid & 63;
  int wr = w >> 1, wc = w & 1;
  int c = l & 15, g = l >> 4;
  f32x4 acc[4][2] = {};
  int r8 = l >> 3;                  // row within the 8-row group = (row & 7)
  int sslot = (l & 7) ^ r8;         // swizzled 16B-slot index in the source row
  const u16* Ag = A + (size_t)(m0 + w*32 + r8)*K + sslot*8;   // 4 loads: rows w*32+i*8
  const u16* Wg = W + (size_t)(n0 + w*16 + r8)*K + sslot*8;   // 2 loads: rows w*16+i*8

#define STAGE(dA, dB, k0) do {                                                          \
  _Pragma("unroll")                                                                     \
  for (int i = 0; i < 4; i++)                                                           \
    __builtin_amdgcn_global_load_lds(                                                   \
        (const __attribute__((address_space(1))) void*)(Ag + (size_t)(i*8)*K + (k0)),   \
        (__attribute__((address_space(3))) void*)(dA + (w*32 + i*8)*64), 16, 0, 0);     \
  _Pragma("unroll")                                                                     \
  for (int i = 0; i < 2; i++)                                                           \
    __builtin_amdgcn_global_load_lds(                                                   \
        (const __attribute__((address_space(1))) void*)(Wg + (size_t)(i*8)*K + (k0)),   \
        (__attribute__((address_space(3))) void*)(dB + (w*16 + i*8)*64), 16, 0, 0);     \
  } while (0)

  // Read side: row r, k-slice ks*32+g*8 -> logical 16B slot j=ks*4+g, physical
  // slot j^(r&7) = j^(c&7). 16 lanes -> 8 distinct slots -> 2-way (free).
#define COMPUTE(sA, sB) do {                                                            \
  _Pragma("unroll")                                                                     \
  for (int ks = 0; ks < 2; ks++) {                                                      \
    s16x8 af[4], bq[2];                                                                 \
    int sl = ((ks*4 + g) ^ (c & 7)) * 8;                                                \
    _Pragma("unroll")                                                                   \
    for (int mt = 0; mt < 4; mt++)                                                      \
      af[mt] = *(const s16x8*)(sA + (wr*64 + mt*16 + c)*64 + sl);                       \
    _Pragma("unroll")                                                                   \
    for (int nt = 0; nt < 2; nt++)                                                      \
      bq[nt] = *(const s16x8*)(sB + (wc*32 + nt*16 + c)*64 + sl);                       \
    _Pragma("unroll")                                                                   \
    for (int mt = 0; mt < 4; mt++)                                                      \
      _Pragma("unroll")                                                                 \
      for (int nt = 0; nt < 2; nt++)                                                    \
        acc[mt][nt] = __builtin_amdgcn_mfma_f32_16x16x32_bf16(af[mt], bq[nt],           \
                                                              acc[mt][nt], 0, 0, 0);    \
  } } while (0)

  const int NT = K >> 6;            // 24 K-tiles of 64 (even, >= 4)
  STAGE(As0, Bs0, 0);
  STAGE(As1, Bs1, 64);
  WAITBAR(6);                       // tile0 landed; tile1 in flight
  for (int t = 0; t + 2 < NT; t += 2) {
    COMPUTE(As0, Bs0);              // tile t (landed)
    RAWBAR();                       // all waves done reading As0/Bs0
    STAGE(As0, Bs0, (t+2)*64);
    WAITBAR(6);                     // tile t+1 landed; t+2 in flight
    COMPUTE(As1, Bs1);              // tile t+1
    RAWBAR();                       // all waves done reading As1/Bs1
    if (t + 3 < NT) {
      STAGE(As1, Bs1, (t+3)*64);
      WAITBAR(6);                   // tile t+2 landed; t+3 in flight
    } else {
      WAITBAR(0);
    }
  }
  COMPUTE(As0, Bs0);                // tile NT-2 (landed via last WAITBAR)
  WAITBAR(0);                       // tile NT-1 landed
  COMPUTE(As1, Bs1);                // tile NT-1
#undef STAGE
#undef COMPUTE

#pragma unroll
  for (int mt = 0; mt < 4; mt++)
#pragma unroll
    for (int nt = 0; nt < 2; nt++)
#pragma unroll
      for (int r = 0; r < 4; r++) {
        int m = m0 + wr*64 + mt*16 + g*4 + r;
        int n = n0 + wc*32 + nt*16 + c;
        size_t off = (size_t)m*N + n;
        float vv = acc[mt][nt][r];
        if (F32OUT) {
          ((float*)Cv)[off] = vv + resid[off];
        } else {
          ((u16*)Cv)[off] = f2bf(vv);
        }
      }
}

// ---------------- fused RoPE(q,k) + V transpose (one launch) ----------------
__global__ __launch_bounds__(256) void k_rope_vt(const u16* __restrict__ qkv,
                                                 u16* __restrict__ q,
                                                 u16* __restrict__ k,
                                                 u16* __restrict__ vt,
                                                 const int* __restrict__ spp) {
  __shared__ u16 tile[64][65];
  int bid = blockIdx.x;
  if (bid < ROPE_BLOCKS) {
    int idx = bid * 256 + threadIdx.x;     // (tok*28 + h)*32 + p
    int p = idx & 31;
    int h = (idx >> 5) % 28;
    int tok = idx / 896;
    int s = tok & (S_ - 1);
    int b = tok >> 11;
    float t = (float)(spp[0] + s);
    // 10000^(-p/32) = exp2(-p * log2(10000)/32); avoids the runtime log in powf
    float inv = exp2f((float)p * -0.41524101186f);
    float fr = t * inv;
    float sn, cs;
    sincosf(fr, &sn, &cs);
    int col = (h < NQ_) ? h*64 + 2*p : HID + (h - NQ_)*64 + 2*p;
    unsigned int pr = *(const unsigned int*)(qkv + (size_t)tok*QKVN + col);
    float x1 = bf2f((u16)(pr & 0xffff));
    float x2 = bf2f((u16)(pr >> 16));
    float y1 = x1*cs - x2*sn;
    float y2 = x2*cs + x1*sn;
    unsigned int outp = (unsigned int)f2bf(y1) | ((unsigned int)f2bf(y2) << 16);
    if (h < NQ_) {
      *(unsigned int*)(q + (((size_t)(b*NQ_ + h))*S_ + s)*64 + 2*p) = outp;
    } else {
      *(unsigned int*)(k + (((size_t)(b*NKV_ + (h - NQ_)))*S_ + s)*64 + 2*p) = outp;
    }
  } else {
    int blk = bid - ROPE_BLOCKS;
    int st = blk & 31;
    int hk = (blk >> 5) & 3;
    int b = blk >> 7;
    int s0 = st * 64;
#pragma unroll
    for (int i = 0; i < 16; i++) {
      int ii = threadIdx.x + i*256;
      int r = ii >> 6, cc = ii & 63;
      tile[r][cc] = qkv[((size_t)(b*S_) + s0 + r)*QKVN + (NQ_+NKV_)*64 + hk*64 + cc];
    }
    __syncthreads();
#pragma unroll
    for (int i = 0; i < 16; i++) {
      int ii = threadIdx.x + i*256;
      int d = ii >> 6, s = ii & 63;
      vt[((size_t)(b*NKV_ + hk)*64 + d)*S_ + s0 + s] = tile[s][d];
    }
  }
}

// ---------------- Flash attention, one wave per (b,h,32-query tile) ----------------
// R15: REVERT to R4-exact (proven 43.4us). R10 falsified the 16-row occupancy play:
// K/V tile loads are a FIXED per-iteration cost (64x64 tiles regardless of q-tile
// height), so halving q-rows doubled load issue per unit compute (62us, MfmaUtil
// 4.4). 32-row amortizes K/V over 2x queries; w=3 is the VGPR-legal occupancy max.
__global__ __launch_bounds__(64, 3) void k_attn(const u16* __restrict__ q,
                                                const u16* __restrict__ k,
                                                const u16* __restrict__ vt,
                                                u16* __restrict__ ao,
                                                const int* __restrict__ spp) {
  __shared__ __align__(16) u16 Pt[32*72];
  int lin = blockIdx.x;
  // XCD-aware swizzle (bid&7 = XCD): each XCD gets all 64 q-tiles of 6 consecutive
  // heads sharing one (b,hk) K/V pair (512KB, L2-resident).
  int xcd = lin & 7, loc = lin >> 3;
  int qb = loc & 63;
  int bh = xcd * 6 + (loc >> 6);   // [0,48)
  int h = bh % NQ_;
  int b = bh / NQ_;
  int q0 = qb * 32;
  int hk = h / (NQ_/NKV_);
  int l = threadIdx.x;
  int c = l & 15, g = l >> 4;
  int sp = spp[0];
  const u16* qptr = q + ((size_t)(b*NQ_ + h))*S_*64;
  const u16* kptr = k + ((size_t)(b*NKV_ + hk))*S_*64;
  const u16* vptr = vt + ((size_t)(b*NKV_ + hk))*64*S_;

  s16x8 qf[2][2];
#pragma unroll
  for (int qt = 0; qt < 2; qt++)
#pragma unroll
    for (int ks = 0; ks < 2; ks++)
      qf[qt][ks] = *(const s16x8*)(qptr + (size_t)(q0 + qt*16 + c)*64 + ks*32 + g*8);

  f32x4 o[4][2] = {};          // o[dt][qt]: O^T accum, row=d col=q
  float m_run[2], l_run[2];
#pragma unroll
  for (int i = 0; i < 2; i++) { m_run[i] = -1e30f; l_run[i] = 0.f; }

  int lo = sp + q0 - 256; if (lo < 0) lo = 0;
  int hi = sp + q0 + 31;  if (hi > S_ - 1) hi = S_ - 1;
  int kt0 = lo >> 6, kt1 = hi >> 6;

  s16x8 kf[4][2];
#pragma unroll
  for (int km = 0; km < 4; km++)
#pragma unroll
    for (int ks = 0; ks < 2; ks++)
      kf[km][ks] = *(const s16x8*)(kptr + (size_t)(kt0*64 + km*16 + c)*64 + ks*32 + g*8);

  for (int kt = kt0; kt <= kt1; kt++) {
    // V(kt) issued first: consumed at PV, covered by QK x2 + kf prefetch + softmax x2.
    s16x8 vf[2][4];
#pragma unroll
    for (int ks = 0; ks < 2; ks++)
#pragma unroll
      for (int dt = 0; dt < 4; dt++)
        vf[ks][dt] = *(const s16x8*)(vptr + (size_t)(dt*16 + c)*S_ + kt*64 + ks*32 + g*8);

    bool full = (kt*64 + 63 <= sp + q0) && (kt*64 >= sp + q0 - 225);
#pragma unroll
    for (int qt = 0; qt < 2; qt++) {
      f32x4 sa[4];               // S^T slice for this qt: row=key col=query
      __builtin_amdgcn_s_setprio(1);
#pragma unroll
      for (int km = 0; km < 4; km++) {
        f32x4 z = {};
        z = __builtin_amdgcn_mfma_f32_16x16x32_bf16(kf[km][0], qf[qt][0], z, 0, 0, 0);
        sa[km] = __builtin_amdgcn_mfma_f32_16x16x32_bf16(kf[km][1], qf[qt][1], z, 0, 0, 0);
      }
      __builtin_amdgcn_s_setprio(0);
      if (qt == 1 && kt < kt1) {
        // K(kt+1) prefetch right after kf's last use; covered by softmax + PV.
#pragma unroll
        for (int km = 0; km < 4; km++)
#pragma unroll
          for (int ks = 0; ks < 2; ks++)
            kf[km][ks] = *(const s16x8*)(kptr + (size_t)((kt+1)*64 + km*16 + c)*64 + ks*32 + g*8);
      }
      float mx = -1e30f;
      if (full) {
#pragma unroll
        for (int km = 0; km < 4; km++)
#pragma unroll
          for (int r = 0; r < 4; r++) {
            float sv = sa[km][r] * 0.125f;
            sa[km][r] = sv;
            mx = fmaxf(mx, sv);
          }
      } else {
        int pos = sp + q0 + qt*16 + c;
#pragma unroll
        for (int km = 0; km < 4; km++)
#pragma unroll
          for (int r = 0; r < 4; r++) {
            int key = kt*64 + km*16 + g*4 + r;
            float sv = sa[km][r] * 0.125f;
            sv = ((unsigned)(pos - key) <= 256u) ? sv : -1e30f;
            sa[km][r] = sv;
            mx = fmaxf(mx, sv);
          }
      }
      mx = fmaxf(mx, __shfl_xor(mx, 16));
      mx = fmaxf(mx, __shfl_xor(mx, 32));
      float mnew = fmaxf(m_run[qt], mx);
      float alpha = __expf(m_run[qt] - mnew);
      m_run[qt] = mnew;
      float rsum = 0.f;
#pragma unroll
      for (int km = 0; km < 4; km++) {
        float p0 = __expf(sa[km][0] - mnew);   // masked -1e30 underflows to 0
        float p1 = __expf(sa[km][1] - mnew);
        float p2 = __expf(sa[km][2] - mnew);
        float p3 = __expf(sa[km][3] - mnew);
        rsum += p0 + p1 + p2 + p3;
        *(unsigned long long*)(Pt + (qt*16 + c)*72 + km*16 + g*4) = pk4bf(p0, p1, p2, p3);
      }
      rsum += __shfl_xor(rsum, 16);
      rsum += __shfl_xor(rsum, 32);
      l_run[qt] = l_run[qt]*alpha + rsum;
#pragma unroll
      for (int dt = 0; dt < 4; dt++) {
        o[dt][qt][0] *= alpha; o[dt][qt][1] *= alpha;
        o[dt][qt][2] *= alpha; o[dt][qt][3] *= alpha;
      }
    }
    LDS_FENCE();   // Pt writes ordered before reads (in-order DS pipe, same wave)
    // PV: O^T += V^T @ P^T
    __builtin_amdgcn_s_setprio(1);
#pragma unroll
    for (int ks = 0; ks < 2; ks++)
#pragma unroll
      for (int qt = 0; qt < 2; qt++) {
        s16x8 pf = *(const s16x8*)(Pt + (qt*16 + c)*72 + ks*32 + g*8);
#pragma unroll
        for (int dt = 0; dt < 4; dt++)
          o[dt][qt] = __builtin_amdgcn_mfma_f32_16x16x32_bf16(vf[ks][dt], pf, o[dt][qt], 0, 0, 0);
      }
    __builtin_amdgcn_s_setprio(0);
    LDS_FENCE();   // Pt reads ordered before next iteration's writes
  }
#pragma unroll
  for (int qt = 0; qt < 2; qt++) {
    float inv = 1.f / l_run[qt];
    int qi = q0 + qt*16 + c;
    u16* row = ao + ((size_t)(b*S_) + qi)*HID + h*64;
#pragma unroll
    for (int dt = 0; dt < 4; dt++)
      *(unsigned long long*)(row + dt*16 + g*4) =
          pk4bf(o[dt][qt][0]*inv, o[dt][qt][1]*inv, o[dt][qt][2]*inv, o[dt][qt][3]*inv);
  }
}

extern "C" void kernel_launch(void* const* d_in, const int* in_sizes, int n_in,
                              void* d_out, int out_size, void* d_ws, size_t ws_size,
                              hipStream_t stream) {
  const float* x_f32    = (const float*)d_in[0];
  const float* g_f32    = (const float*)d_in[1];
  const float* wqkv_f32 = (const float*)d_in[2];
  const float* wout_f32 = (const float*)d_in[3];
  const int*   spp      = (const int*)d_in[4];
  char* ws = (char*)d_ws;
  // workspace layout (bytes), ~57.1 MB total
  u16* wqkvb = (u16*)(ws);                    //  6,291,456
  u16* woutb = (u16*)(ws + 6291456);          //  4,718,592 (contiguous with wqkvb)
  u16* xn    = (u16*)(ws + 11010048);         // 12,582,912
  u16* qkv   = (u16*)(ws + 23592960);         // 16,777,216
  u16* qbuf  = (u16*)(ws + 40370176);         // 12,582,912
  u16* kbuf  = (u16*)(ws + 52953088);         //  2,097,152
  u16* vtb   = (u16*)(ws + 55050240);         //  2,097,152  (end 57,147,392)
  u16* attn  = xn;                            // aliases xn (dead after GEMM1)

  const int nwq4 = QKVN*HID/4, nwo4 = HID*HID/4;
  k_cvt2<<<(nwq4 + nwo4 + 255)/256, 256, 0, stream>>>(wqkv_f32, nwq4, wout_f32, nwo4, wqkvb);
  k_rmsnorm<<<NTOK, 384, 0, stream>>>(x_f32, g_f32, xn);
  k_gemm_bt<false><<<32*(QKVN/64), 256, 0, stream>>>(xn, wqkvb, qkv, nullptr, QKVN, HID);
  k_rope_vt<<<ROPE_BLOCKS + VT_BLOCKS, 256, 0, stream>>>(qkv, qbuf, kbuf, vtb, spp);
  k_attn<<<B_*NQ_*(S_/32), 64, 0, stream>>>(qbuf, kbuf, vtb, attn, spp);
  k_gemm_bt<true><<<32*(HID/64), 256, 0, stream>>>(attn, woutb, d_out, x_f32, HID, HID);
}

// Round 12
// 202.945 us; speedup vs baseline: 1.1210x; 1.0283x over previous
//
#include <hip/hip_runtime.h>
#include <hip/hip_bf16.h>

typedef float f32x4 __attribute__((ext_vector_type(4)));
typedef short s16x8 __attribute__((ext_vector_type(8)));
typedef unsigned short u16;

#define B_ 2
#define S_ 2048
#define HID 1536
#define NQ_ 24
#define NKV_ 4
#define HD 64
#define NTOK (B_*S_)
#define QKVN ((NQ_+2*NKV_)*HD)   // 2048

// fused setup kernel job split
#define CVT_BLKS  ((QKVN*HID + HID*HID)/4/256)   // 5376
#define RMS_BLKS  NTOK                            // 4096
#define TAB_BLKS  (S_*32/256)                     // 256
#define SETUP_BLKS (CVT_BLKS + RMS_BLKS + TAB_BLKS)

#define ROPE2_BLOCKS ((NTOK*28*16)/256)  // 7168 (2 rot-pairs per thread)
#define VT_BLOCKS (B_*NKV_*(S_/64))      // 256

// Compiler-only memory fence (single-wave block: LDS pipe is in-order, no s_barrier
// needed -> avoids the vmcnt(0) drain). Proven R6->R7 on k_attn.
#define LDS_FENCE() asm volatile("" ::: "memory")

// Counted-vmcnt barrier pair (T4): wait for all but the newest N loads, then raw
// s_barrier -- deliberately does NOT drain the in-flight prefetch.
#define WAITBAR(n) asm volatile("s_waitcnt vmcnt(" #n ")\n\ts_barrier" ::: "memory")
#define RAWBAR()   asm volatile("s_barrier" ::: "memory")

__device__ __forceinline__ float bf2f(u16 u) {
  unsigned int x = ((unsigned int)u) << 16;
  float f; __builtin_memcpy(&f, &x, 4); return f;
}
__device__ __forceinline__ u16 f2bf(float f) {
  unsigned int u; __builtin_memcpy(&u, &f, 4);
  u += 0x7fffu + ((u >> 16) & 1u);
  return (u16)(u >> 16);
}
// 4x f32 -> packed bf16x4 via v_cvt_pk_bf16_f32
__device__ __forceinline__ unsigned long long pk4bf(float a, float b, float c, float d) {
  __hip_bfloat162 x = __float22bfloat162_rn(make_float2(a, b));
  __hip_bfloat162 y = __float22bfloat162_rn(make_float2(c, d));
  unsigned int xi, yi;
  __builtin_memcpy(&xi, &x, 4);
  __builtin_memcpy(&yi, &y, 4);
  return (unsigned long long)xi | ((unsigned long long)yi << 32);
}

// ---------------- fused setup: weight cvt + RMSNorm + RoPE cos/sin table ----------------
// R16: one launch instead of three jobs' worth of serialization. Jobs are
// block-range-split (uniform branch per block):
//   [0, CVT_BLKS)            : fp32->bf16 of w_qkv and w_out (contiguous dsts)
//   [CVT_BLKS, +RMS_BLKS)    : RMSNorm row per block (256 thr, 192 active x 8 elems)
//   [.., +TAB_BLKS)          : cos/sin table (65536 entries) -- bakes start_pos;
//                              lives in d_out's buffer (dead until GEMM2 writes it).
__global__ __launch_bounds__(256) void k_setup(const float* __restrict__ x,
                                               const float* __restrict__ g,
                                               const float* __restrict__ wq,
                                               const float* __restrict__ wo,
                                               u16* __restrict__ wb,
                                               u16* __restrict__ xn,
                                               float2* __restrict__ tab,
                                               const int* __restrict__ spp) {
  int bid = blockIdx.x, tid = threadIdx.x;
  if (bid < CVT_BLKS) {
    int i = bid * 256 + tid;   // quad index
    const int n0q = QKVN*HID/4;
    const float* src = (i < n0q) ? wq : wo;
    int j = (i < n0q) ? i : i - n0q;
    f32x4 v = ((const f32x4*)src)[j];
    *(unsigned long long*)(wb + (size_t)i*4) = pk4bf(v[0], v[1], v[2], v[3]);
  } else if (bid < CVT_BLKS + RMS_BLKS) {
    int row = bid - CVT_BLKS;
    const f32x4* xr = (const f32x4*)(x + (size_t)row * HID);
    f32x4 v0 = {}, v1 = {};
    float ss = 0.f;
    if (tid < 192) {
      v0 = xr[2*tid]; v1 = xr[2*tid + 1];
      ss = v0[0]*v0[0] + v0[1]*v0[1] + v0[2]*v0[2] + v0[3]*v0[3]
         + v1[0]*v1[0] + v1[1]*v1[1] + v1[2]*v1[2] + v1[3]*v1[3];
    }
#pragma unroll
    for (int off = 1; off < 64; off <<= 1) ss += __shfl_xor(ss, off);
    __shared__ float red[4];
    if ((tid & 63) == 0) red[tid >> 6] = ss;
    __syncthreads();
    float rs = rsqrtf((red[0] + red[1] + red[2] + red[3]) * (1.f/HID) + 1e-6f);
    if (tid < 192) {
      const f32x4* gr = (const f32x4*)g;
      f32x4 g0 = gr[2*tid], g1 = gr[2*tid + 1];
      unsigned long long* out = (unsigned long long*)(xn + (size_t)row * HID);
      out[2*tid]     = pk4bf(v0[0]*rs*g0[0], v0[1]*rs*g0[1], v0[2]*rs*g0[2], v0[3]*rs*g0[3]);
      out[2*tid + 1] = pk4bf(v1[0]*rs*g1[0], v1[1]*rs*g1[1], v1[2]*rs*g1[2], v1[3]*rs*g1[3]);
    }
  } else {
    int i = (bid - CVT_BLKS - RMS_BLKS) * 256 + tid;   // [0, 65536)
    int s = i >> 5, p = i & 31;
    float t = (float)(spp[0] + s);
    // 10000^(-p/32) = exp2(-p*log2(1e4)/32)
    float inv = exp2f((float)p * -0.41524101186f);
    float sn, cs;
    sincosf(t * inv, &sn, &cs);
    tab[i] = make_float2(cs, sn);
  }
}

// ---------------- GEMM C[M][N] = A[M][K] @ W[N][K]^T, M fixed = 4096 ----------------
// R15 (kept): BN=64 -> GEMM1 1024 blocks (4/CU), GEMM2 768 (3/CU); 48KB LDS -> 3
// resident blocks/CU = 12 waves/CU; counted vmcnt(6) depth-2 pipeline; T2 XOR
// slot-swizzle (pre-swizzled global source, same XOR on read); XCD M-stripe.
template <bool F32OUT>
__global__ __launch_bounds__(256) void k_gemm_bt(const u16* __restrict__ A,
                                                 const u16* __restrict__ W,
                                                 void* __restrict__ Cv,
                                                 const float* __restrict__ resid,
                                                 int N, int K) {
  __shared__ __align__(16) u16 As0[128*64], Bs0[64*64];
  __shared__ __align__(16) u16 As1[128*64], Bs1[64*64];
  int lin = blockIdx.x;
  int xcd = lin & 7, loc = lin >> 3;
  int mloc = loc & 3, nloc = loc >> 2;          // stripe height 4 (32 Mtiles / 8 XCDs)
  int m0 = (xcd*4 + mloc) * 128, n0 = nloc * 64;
  int tid = threadIdx.x;
  int w = tid >> 6, l = tid & 63;
  int wr = w >> 1, wc = w & 1;
  int c = l & 15, g = l >> 4;
  f32x4 acc[4][2] = {};
  int r8 = l >> 3;                  // row within the 8-row group = (row & 7)
  int sslot = (l & 7) ^ r8;         // swizzled 16B-slot index in the source row
  const u16* Ag = A + (size_t)(m0 + w*32 + r8)*K + sslot*8;   // 4 loads: rows w*32+i*8
  const u16* Wg = W + (size_t)(n0 + w*16 + r8)*K + sslot*8;   // 2 loads: rows w*16+i*8

#define STAGE(dA, dB, k0) do {                                                          \
  _Pragma("unroll")                                                                     \
  for (int i = 0; i < 4; i++)                                                           \
    __builtin_amdgcn_global_load_lds(                                                   \
        (const __attribute__((address_space(1))) void*)(Ag + (size_t)(i*8)*K + (k0)),   \
        (__attribute__((address_space(3))) void*)(dA + (w*32 + i*8)*64), 16, 0, 0);     \
  _Pragma("unroll")                                                                     \
  for (int i = 0; i < 2; i++)                                                           \
    __builtin_amdgcn_global_load_lds(                                                   \
        (const __attribute__((address_space(1))) void*)(Wg + (size_t)(i*8)*K + (k0)),   \
        (__attribute__((address_space(3))) void*)(dB + (w*16 + i*8)*64), 16, 0, 0);     \
  } while (0)

#define COMPUTE(sA, sB) do {                                                            \
  _Pragma("unroll")                                                                     \
  for (int ks = 0; ks < 2; ks++) {                                                      \
    s16x8 af[4], bq[2];                                                                 \
    int sl = ((ks*4 + g) ^ (c & 7)) * 8;                                                \
    _Pragma("unroll")                                                                   \
    for (int mt = 0; mt < 4; mt++)                                                      \
      af[mt] = *(const s16x8*)(sA + (wr*64 + mt*16 + c)*64 + sl);                       \
    _Pragma("unroll")                                                                   \
    for (int nt = 0; nt < 2; nt++)                                                      \
      bq[nt] = *(const s16x8*)(sB + (wc*32 + nt*16 + c)*64 + sl);                       \
    _Pragma("unroll")                                                                   \
    for (int mt = 0; mt < 4; mt++)                                                      \
      _Pragma("unroll")                                                                 \
      for (int nt = 0; nt < 2; nt++)                                                    \
        acc[mt][nt] = __builtin_amdgcn_mfma_f32_16x16x32_bf16(af[mt], bq[nt],           \
                                                              acc[mt][nt], 0, 0, 0);    \
  } } while (0)

  const int NT = K >> 6;            // 24 K-tiles of 64 (even, >= 4)
  STAGE(As0, Bs0, 0);
  STAGE(As1, Bs1, 64);
  WAITBAR(6);                       // tile0 landed; tile1 in flight
  for (int t = 0; t + 2 < NT; t += 2) {
    COMPUTE(As0, Bs0);              // tile t (landed)
    RAWBAR();                       // all waves done reading As0/Bs0
    STAGE(As0, Bs0, (t+2)*64);
    WAITBAR(6);                     // tile t+1 landed; t+2 in flight
    COMPUTE(As1, Bs1);              // tile t+1
    RAWBAR();                       // all waves done reading As1/Bs1
    if (t + 3 < NT) {
      STAGE(As1, Bs1, (t+3)*64);
      WAITBAR(6);                   // tile t+2 landed; t+3 in flight
    } else {
      WAITBAR(0);
    }
  }
  COMPUTE(As0, Bs0);                // tile NT-2 (landed via last WAITBAR)
  WAITBAR(0);                       // tile NT-1 landed
  COMPUTE(As1, Bs1);                // tile NT-1
#undef STAGE
#undef COMPUTE

#pragma unroll
  for (int mt = 0; mt < 4; mt++)
#pragma unroll
    for (int nt = 0; nt < 2; nt++)
#pragma unroll
      for (int r = 0; r < 4; r++) {
        int m = m0 + wr*64 + mt*16 + g*4 + r;
        int n = n0 + wc*32 + nt*16 + c;
        size_t off = (size_t)m*N + n;
        float vv = acc[mt][nt][r];
        if (F32OUT) {
          ((float*)Cv)[off] = vv + resid[off];
        } else {
          ((u16*)Cv)[off] = f2bf(vv);
        }
      }
}

// ---------------- fused RoPE(q,k) + V transpose (one launch) ----------------
// R16: table-based rotation (cos/sin from k_setup's table in d_out) -- removes
// sincosf/exp2f (~70 VALU) from every thread; each thread now does TWO rotation
// pairs (8B load / 16B table / 8B store).
__global__ __launch_bounds__(256) void k_rope_vt(const u16* __restrict__ qkv,
                                                 u16* __restrict__ q,
                                                 u16* __restrict__ k,
                                                 u16* __restrict__ vt,
                                                 const float2* __restrict__ tab) {
  __shared__ u16 tile[64][65];
  int bid = blockIdx.x;
  if (bid < ROPE2_BLOCKS) {
    int idx = bid * 256 + threadIdx.x;     // (tok*28 + h)*16 + j ; j covers p=2j,2j+1
    int j = idx & 15;
    int h = (idx >> 4) % 28;
    int tok = idx / 448;
    int s = tok & (S_ - 1);
    int b = tok >> 11;
    f32x4 cs = *(const f32x4*)(tab + (size_t)s*32 + 2*j);   // c0,s0,c1,s1 (16B aligned)
    int col = (h < NQ_) ? h*64 + 4*j : HID + (h - NQ_)*64 + 4*j;
    unsigned long long pr = *(const unsigned long long*)(qkv + (size_t)tok*QKVN + col);
    float x1a = bf2f((u16)pr),         x2a = bf2f((u16)(pr >> 16));
    float x1b = bf2f((u16)(pr >> 32)), x2b = bf2f((u16)(pr >> 48));
    float ya1 = x1a*cs[0] - x2a*cs[1];
    float ya2 = x2a*cs[0] + x1a*cs[1];
    float yb1 = x1b*cs[2] - x2b*cs[3];
    float yb2 = x2b*cs[2] + x1b*cs[3];
    unsigned long long outp = pk4bf(ya1, ya2, yb1, yb2);
    if (h < NQ_) {
      *(unsigned long long*)(q + (((size_t)(b*NQ_ + h))*S_ + s)*64 + 4*j) = outp;
    } else {
      *(unsigned long long*)(k + (((size_t)(b*NKV_ + (h - NQ_)))*S_ + s)*64 + 4*j) = outp;
    }
  } else {
    int blk = bid - ROPE2_BLOCKS;
    int st = blk & 31;
    int hk = (blk >> 5) & 3;
    int b = blk >> 7;
    int s0 = st * 64;
#pragma unroll
    for (int i = 0; i < 16; i++) {
      int ii = threadIdx.x + i*256;
      int r = ii >> 6, cc = ii & 63;
      tile[r][cc] = qkv[((size_t)(b*S_) + s0 + r)*QKVN + (NQ_+NKV_)*64 + hk*64 + cc];
    }
    __syncthreads();
#pragma unroll
    for (int i = 0; i < 16; i++) {
      int ii = threadIdx.x + i*256;
      int d = ii >> 6, s = ii & 63;
      vt[((size_t)(b*NKV_ + hk)*64 + d)*S_ + s0 + s] = tile[s][d];
    }
  }
}

// ---------------- Flash attention, one wave per (b,h,32-query tile) ----------------
// R15/R4-exact (proven 43.4us): 32-row tiles, (64,3), 84 VGPR, no spill. XCD swizzle
// (one (b,hk) per XCD -> K/V L2-resident), deep prefetch, per-qt softmax, setprio.
// R10 falsified 16-row tiles (fixed K/V load cost per iteration doubles); R7/R8
// established VGPR budget ~256*2/min_waves -> w=3 is the legal occupancy max.
__global__ __launch_bounds__(64, 3) void k_attn(const u16* __restrict__ q,
                                                const u16* __restrict__ k,
                                                const u16* __restrict__ vt,
                                                u16* __restrict__ ao,
                                                const int* __restrict__ spp) {
  __shared__ __align__(16) u16 Pt[32*72];
  int lin = blockIdx.x;
  int xcd = lin & 7, loc = lin >> 3;
  int qb = loc & 63;
  int bh = xcd * 6 + (loc >> 6);   // [0,48)
  int h = bh % NQ_;
  int b = bh / NQ_;
  int q0 = qb * 32;
  int hk = h / (NQ_/NKV_);
  int l = threadIdx.x;
  int c = l & 15, g = l >> 4;
  int sp = spp[0];
  const u16* qptr = q + ((size_t)(b*NQ_ + h))*S_*64;
  const u16* kptr = k + ((size_t)(b*NKV_ + hk))*S_*64;
  const u16* vptr = vt + ((size_t)(b*NKV_ + hk))*64*S_;

  s16x8 qf[2][2];
#pragma unroll
  for (int qt = 0; qt < 2; qt++)
#pragma unroll
    for (int ks = 0; ks < 2; ks++)
      qf[qt][ks] = *(const s16x8*)(qptr + (size_t)(q0 + qt*16 + c)*64 + ks*32 + g*8);

  f32x4 o[4][2] = {};          // o[dt][qt]: O^T accum, row=d col=q
  float m_run[2], l_run[2];
#pragma unroll
  for (int i = 0; i < 2; i++) { m_run[i] = -1e30f; l_run[i] = 0.f; }

  int lo = sp + q0 - 256; if (lo < 0) lo = 0;
  int hi = sp + q0 + 31;  if (hi > S_ - 1) hi = S_ - 1;
  int kt0 = lo >> 6, kt1 = hi >> 6;

  s16x8 kf[4][2];
#pragma unroll
  for (int km = 0; km < 4; km++)
#pragma unroll
    for (int ks = 0; ks < 2; ks++)
      kf[km][ks] = *(const s16x8*)(kptr + (size_t)(kt0*64 + km*16 + c)*64 + ks*32 + g*8);

  for (int kt = kt0; kt <= kt1; kt++) {
    s16x8 vf[2][4];
#pragma unroll
    for (int ks = 0; ks < 2; ks++)
#pragma unroll
      for (int dt = 0; dt < 4; dt++)
        vf[ks][dt] = *(const s16x8*)(vptr + (size_t)(dt*16 + c)*S_ + kt*64 + ks*32 + g*8);

    bool full = (kt*64 + 63 <= sp + q0) && (kt*64 >= sp + q0 - 225);
#pragma unroll
    for (int qt = 0; qt < 2; qt++) {
      f32x4 sa[4];               // S^T slice for this qt: row=key col=query
      __builtin_amdgcn_s_setprio(1);
#pragma unroll
      for (int km = 0; km < 4; km++) {
        f32x4 z = {};
        z = __builtin_amdgcn_mfma_f32_16x16x32_bf16(kf[km][0], qf[qt][0], z, 0, 0, 0);
        sa[km] = __builtin_amdgcn_mfma_f32_16x16x32_bf16(kf[km][1], qf[qt][1], z, 0, 0, 0);
      }
      __builtin_amdgcn_s_setprio(0);
      if (qt == 1 && kt < kt1) {
#pragma unroll
        for (int km = 0; km < 4; km++)
#pragma unroll
          for (int ks = 0; ks < 2; ks++)
            kf[km][ks] = *(const s16x8*)(kptr + (size_t)((kt+1)*64 + km*16 + c)*64 + ks*32 + g*8);
      }
      float mx = -1e30f;
      if (full) {
#pragma unroll
        for (int km = 0; km < 4; km++)
#pragma unroll
          for (int r = 0; r < 4; r++) {
            float sv = sa[km][r] * 0.125f;
            sa[km][r] = sv;
            mx = fmaxf(mx, sv);
          }
      } else {
        int pos = sp + q0 + qt*16 + c;
#pragma unroll
        for (int km = 0; km < 4; km++)
#pragma unroll
          for (int r = 0; r < 4; r++) {
            int key = kt*64 + km*16 + g*4 + r;
            float sv = sa[km][r] * 0.125f;
            sv = ((unsigned)(pos - key) <= 256u) ? sv : -1e30f;
            sa[km][r] = sv;
            mx = fmaxf(mx, sv);
          }
      }
      mx = fmaxf(mx, __shfl_xor(mx, 16));
      mx = fmaxf(mx, __shfl_xor(mx, 32));
      float mnew = fmaxf(m_run[qt], mx);
      float alpha = __expf(m_run[qt] - mnew);
      m_run[qt] = mnew;
      float rsum = 0.f;
#pragma unroll
      for (int km = 0; km < 4; km++) {
        float p0 = __expf(sa[km][0] - mnew);   // masked -1e30 underflows to 0
        float p1 = __expf(sa[km][1] - mnew);
        float p2 = __expf(sa[km][2] - mnew);
        float p3 = __expf(sa[km][3] - mnew);
        rsum += p0 + p1 + p2 + p3;
        *(unsigned long long*)(Pt + (qt*16 + c)*72 + km*16 + g*4) = pk4bf(p0, p1, p2, p3);
      }
      rsum += __shfl_xor(rsum, 16);
      rsum += __shfl_xor(rsum, 32);
      l_run[qt] = l_run[qt]*alpha + rsum;
#pragma unroll
      for (int dt = 0; dt < 4; dt++) {
        o[dt][qt][0] *= alpha; o[dt][qt][1] *= alpha;
        o[dt][qt][2] *= alpha; o[dt][qt][3] *= alpha;
      }
    }
    LDS_FENCE();   // Pt writes ordered before reads (in-order DS pipe, same wave)
    // PV: O^T += V^T @ P^T
    __builtin_amdgcn_s_setprio(1);
#pragma unroll
    for (int ks = 0; ks < 2; ks++)
#pragma unroll
      for (int qt = 0; qt < 2; qt++) {
        s16x8 pf = *(const s16x8*)(Pt + (qt*16 + c)*72 + ks*32 + g*8);
#pragma unroll
        for (int dt = 0; dt < 4; dt++)
          o[dt][qt] = __builtin_amdgcn_mfma_f32_16x16x32_bf16(vf[ks][dt], pf, o[dt][qt], 0, 0, 0);
      }
    __builtin_amdgcn_s_setprio(0);
    LDS_FENCE();   // Pt reads ordered before next iteration's writes
  }
#pragma unroll
  for (int qt = 0; qt < 2; qt++) {
    float inv = 1.f / l_run[qt];
    int qi = q0 + qt*16 + c;
    u16* row = ao + ((size_t)(b*S_) + qi)*HID + h*64;
#pragma unroll
    for (int dt = 0; dt < 4; dt++)
      *(unsigned long long*)(row + dt*16 + g*4) =
          pk4bf(o[dt][qt][0]*inv, o[dt][qt][1]*inv, o[dt][qt][2]*inv, o[dt][qt][3]*inv);
  }
}

extern "C" void kernel_launch(void* const* d_in, const int* in_sizes, int n_in,
                              void* d_out, int out_size, void* d_ws, size_t ws_size,
                              hipStream_t stream) {
  const float* x_f32    = (const float*)d_in[0];
  const float* g_f32    = (const float*)d_in[1];
  const float* wqkv_f32 = (const float*)d_in[2];
  const float* wout_f32 = (const float*)d_in[3];
  const int*   spp      = (const int*)d_in[4];
  char* ws = (char*)d_ws;
  // workspace layout (bytes), ~57.1 MB total
  u16* wqkvb = (u16*)(ws);                    //  6,291,456
  u16* woutb = (u16*)(ws + 6291456);          //  4,718,592 (contiguous with wqkvb)
  u16* xn    = (u16*)(ws + 11010048);         // 12,582,912
  u16* qkv   = (u16*)(ws + 23592960);         // 16,777,216
  u16* qbuf  = (u16*)(ws + 40370176);         // 12,582,912
  u16* kbuf  = (u16*)(ws + 52953088);         //  2,097,152
  u16* vtb   = (u16*)(ws + 55050240);         //  2,097,152  (end 57,147,392)
  u16* attn  = xn;                            // aliases xn (dead after GEMM1)
  // RoPE table lives in d_out's buffer (512KB of 25MB; dead until GEMM2 writes it)
  float2* tab = (float2*)d_out;

  k_setup<<<SETUP_BLKS, 256, 0, stream>>>(x_f32, g_f32, wqkv_f32, wout_f32,
                                          wqkvb, xn, tab, spp);
  k_gemm_bt<false><<<32*(QKVN/64), 256, 0, stream>>>(xn, wqkvb, qkv, nullptr, QKVN, HID);
  k_rope_vt<<<ROPE2_BLOCKS + VT_BLOCKS, 256, 0, stream>>>(qkv, qbuf, kbuf, vtb,
                                                          (const float2*)tab);
  k_attn<<<B_*NQ_*(S_/32), 64, 0, stream>>>(qbuf, kbuf, vtb, attn, spp);
  k_gemm_bt<true><<<32*(HID/64), 256, 0, stream>>>(attn, woutb, d_out, x_f32, HID, HID);
}